// Round 1
// baseline (5884.031 us; speedup 1.0000x reference)
//
#include <hip/hip_runtime.h>
#include <math.h>

#define N_BASIS 16
#define HIDDEN 64
#define OUT_DIM 128
#define NN 100000
#define NE 1600000

__device__ __forceinline__ float silu_f(float x) {
    return x / (1.0f + __expf(-x));
}

// feat[0:16] = rbf(d), feat[16:32] = sh(u) @ sh_w + sh_b
__device__ __forceinline__ void compute_feat(
    float rx, float ry, float rz,
    const float* __restrict__ sC, const float* __restrict__ sWd,
    const float* __restrict__ sShW, const float* __restrict__ sShB,
    float* feat)
{
    float d2 = rx*rx + ry*ry + rz*rz;
    float d = fmaxf(sqrtf(d2), 1e-6f);
    float inv = 1.0f / d;
    float ux = rx*inv, uy = ry*inv, uz = rz*inv;
    #pragma unroll
    for (int m = 0; m < 16; ++m) {
        float t = d - sC[m];
        feat[m] = __expf(-fabsf(sWd[m]) * t * t);
    }
    const float c0 = 0.28209479177387814f;
    const float c1 = 0.4886025119029199f;
    const float c2 = 1.0925484305920792f;
    const float c3 = 0.31539156525252005f;
    const float c4 = 0.5462742152960396f;
    float sh0 = c0;
    float sh1 = c1*uy, sh2 = c1*uz, sh3 = c1*ux;
    float sh4 = c2*ux*uy, sh5 = c2*uy*uz;
    float sh6 = c3*(2.0f*uz*uz - ux*ux - uy*uy);
    float sh7 = c2*ux*uz, sh8 = c4*(ux*ux - uy*uy);
    #pragma unroll
    for (int m = 0; m < 16; ++m) {
        float a = sShB[m];
        a += sh0*sShW[0*16+m]; a += sh1*sShW[1*16+m]; a += sh2*sShW[2*16+m];
        a += sh3*sShW[3*16+m]; a += sh4*sShW[4*16+m]; a += sh5*sShW[5*16+m];
        a += sh6*sShW[6*16+m]; a += sh7*sShW[7*16+m]; a += sh8*sShW[8*16+m];
        feat[16+m] = a;
    }
}

// Per-node zinc branch: zn_f[n][64] = silu(zfeat @ zn_w + zn_b)
__global__ __launch_bounds__(256) void zn_kernel(
    const float* __restrict__ pos, const float* __restrict__ zinc_pos,
    const float* __restrict__ rbf_c, const float* __restrict__ rbf_w,
    const float* __restrict__ sh_w, const float* __restrict__ sh_b,
    const float* __restrict__ zn_w, const float* __restrict__ zn_b,
    float* __restrict__ zn_f)
{
    __shared__ float sW[2048];
    __shared__ float sShW[144], sShB[16], sC[16], sWd[16], sB[64];
    int tid = threadIdx.x;
    for (int i = tid; i < 2048; i += 256) sW[i] = zn_w[i];
    if (tid < 144) sShW[tid] = sh_w[tid];
    if (tid < 16) { sShB[tid] = sh_b[tid]; sC[tid] = rbf_c[tid]; sWd[tid] = rbf_w[tid]; }
    if (tid < 64) sB[tid] = zn_b[tid];
    __syncthreads();
    int n = blockIdx.x * 256 + tid;
    if (n >= NN) return;
    float rx = pos[n*3+0] - zinc_pos[0];
    float ry = pos[n*3+1] - zinc_pos[1];
    float rz = pos[n*3+2] - zinc_pos[2];
    float feat[32];
    compute_feat(rx, ry, rz, sC, sWd, sShW, sShB, feat);
    #pragma unroll 1
    for (int jc = 0; jc < 8; ++jc) {
        float h[8];
        #pragma unroll
        for (int jj = 0; jj < 8; ++jj) h[jj] = sB[jc*8+jj];
        #pragma unroll
        for (int k = 0; k < 32; ++k) {
            float f = feat[k];
            #pragma unroll
            for (int jj = 0; jj < 8; ++jj) h[jj] += f * sW[k*64 + jc*8 + jj];
        }
        #pragma unroll
        for (int jj = 0; jj < 8; ++jj)
            zn_f[(size_t)n*64 + jc*8 + jj] = silu_f(h[jj]);
    }
}

// Per-edge MLP + scatter-add into agg[src][64]
__global__ __launch_bounds__(256) void edge_kernel(
    const float* __restrict__ pos, const int* __restrict__ edge_index,
    const float* __restrict__ rbf_c, const float* __restrict__ rbf_w,
    const float* __restrict__ sh_w, const float* __restrict__ sh_b,
    const float* __restrict__ w1, const float* __restrict__ b1,
    const float* __restrict__ w2, const float* __restrict__ b2,
    float* __restrict__ agg)
{
    __shared__ float sW1[2048];
    __shared__ float sW2[4096];
    __shared__ float sShW[144], sShB[16], sC[16], sWd[16], sB1[64], sB2[64];
    int tid = threadIdx.x;
    for (int i = tid; i < 2048; i += 256) sW1[i] = w1[i];
    for (int i = tid; i < 4096; i += 256) sW2[i] = w2[i];
    if (tid < 144) sShW[tid] = sh_w[tid];
    if (tid < 16) { sShB[tid] = sh_b[tid]; sC[tid] = rbf_c[tid]; sWd[tid] = rbf_w[tid]; }
    if (tid < 64) sB1[tid] = b1[tid];
    if (tid >= 64 && tid < 128) sB2[tid-64] = b2[tid-64];
    __syncthreads();

    int e = blockIdx.x * 256 + tid;   // grid is exact: NE/256 == 6250
    int s   = edge_index[e];
    int dst = edge_index[NE + e];
    const float* ps = pos + 3*(size_t)s;
    const float* pd = pos + 3*(size_t)dst;
    float rx = pd[0]-ps[0], ry = pd[1]-ps[1], rz = pd[2]-ps[2];
    float feat[32];
    compute_feat(rx, ry, rz, sC, sWd, sShW, sShB, feat);

    float h2[64];
    #pragma unroll
    for (int o = 0; o < 64; ++o) h2[o] = sB2[o];   // pm_b2 is per-edge (summed by segment_sum)

    #pragma unroll 1
    for (int jc = 0; jc < 8; ++jc) {
        float h1c[8];
        #pragma unroll
        for (int jj = 0; jj < 8; ++jj) h1c[jj] = sB1[jc*8+jj];
        #pragma unroll
        for (int k = 0; k < 32; ++k) {
            float f = feat[k];
            #pragma unroll
            for (int jj = 0; jj < 8; ++jj) h1c[jj] += f * sW1[k*64 + jc*8 + jj];
        }
        #pragma unroll
        for (int jj = 0; jj < 8; ++jj) h1c[jj] = silu_f(h1c[jj]);
        #pragma unroll
        for (int jj = 0; jj < 8; ++jj) {
            float v = h1c[jj];
            #pragma unroll
            for (int o = 0; o < 64; ++o) h2[o] += v * sW2[(jc*8+jj)*64 + o];
        }
    }
    size_t base = (size_t)s * 64;
    #pragma unroll
    for (int o = 0; o < 64; ++o)
        unsafeAtomicAdd(&agg[base + o], h2[o]);   // global_atomic_add_f32
}

// h = [agg, zn_f] @ np_w + np_b ; LayerNorm ; SiLU
__global__ __launch_bounds__(256) void out_kernel(
    const float* __restrict__ agg, const float* __restrict__ zn_f,
    const float* __restrict__ np_w, const float* __restrict__ np_b,
    const float* __restrict__ ln_g, const float* __restrict__ ln_b,
    float* __restrict__ out)
{
    __shared__ float sX[128*36];   // x transposed: [k][n], 32 nodes/tile, pad 36
    __shared__ float sH[32*130];   // h: [n][o], pad 130
    __shared__ float sMu[32], sVar[32];
    int tid = threadIdx.x;
    int o = tid & 127;
    int nb = (tid >> 7) * 16;      // this thread covers nodes nb..nb+15 of the tile
    float bias = np_b[o];
    float g = ln_g[o], bta = ln_b[o];

    for (int n0 = blockIdx.x * 32; n0 < NN; n0 += gridDim.x * 32) {   // NN/32 = 3125 exact
        for (int i = tid; i < 4096; i += 256) {
            int n = i >> 7, k = i & 127;
            float v = (k < 64) ? agg[(size_t)(n0+n)*64 + k]
                               : zn_f[(size_t)(n0+n)*64 + (k-64)];
            sX[k*36 + n] = v;
        }
        __syncthreads();
        float acc[16];
        #pragma unroll
        for (int i = 0; i < 16; ++i) acc[i] = bias;
        #pragma unroll 4
        for (int k = 0; k < 128; ++k) {
            float w = np_w[k*128 + o];
            const float* xr = &sX[k*36 + nb];
            #pragma unroll
            for (int i = 0; i < 16; ++i) acc[i] += w * xr[i];
        }
        #pragma unroll
        for (int i = 0; i < 16; ++i) sH[(nb+i)*130 + o] = acc[i];
        __syncthreads();
        if (tid < 32) {
            float s = 0.0f, sq = 0.0f;
            for (int oo = 0; oo < 128; ++oo) {
                float v = sH[tid*130 + oo];
                s += v; sq += v*v;
            }
            float mu = s * (1.0f/128.0f);
            sMu[tid] = mu;
            sVar[tid] = sq * (1.0f/128.0f) - mu*mu;
        }
        __syncthreads();
        #pragma unroll
        for (int i = 0; i < 16; ++i) {
            int n = nb + i;
            float y = (acc[i] - sMu[n]) * rsqrtf(sVar[n] + 1e-5f) * g + bta;
            out[(size_t)(n0+n)*128 + o] = silu_f(y);
        }
        __syncthreads();
    }
}

extern "C" void kernel_launch(void* const* d_in, const int* in_sizes, int n_in,
                              void* d_out, int out_size, void* d_ws, size_t ws_size,
                              hipStream_t stream) {
    const float* pos   = (const float*)d_in[0];
    const float* zinc  = (const float*)d_in[1];
    const int*   ei    = (const int*)  d_in[2];
    const float* rbf_c = (const float*)d_in[3];
    const float* rbf_w = (const float*)d_in[4];
    const float* sh_w  = (const float*)d_in[5];
    const float* sh_b  = (const float*)d_in[6];
    const float* pm_w1 = (const float*)d_in[7];
    const float* pm_b1 = (const float*)d_in[8];
    const float* pm_w2 = (const float*)d_in[9];
    const float* pm_b2 = (const float*)d_in[10];
    const float* zn_w  = (const float*)d_in[11];
    const float* zn_b  = (const float*)d_in[12];
    const float* np_w  = (const float*)d_in[13];
    const float* np_b  = (const float*)d_in[14];
    const float* ln_g  = (const float*)d_in[15];
    const float* ln_b  = (const float*)d_in[16];
    float* out  = (float*)d_out;
    float* agg  = (float*)d_ws;                       // NN*64 floats
    float* zn_f = agg + (size_t)NN * 64;              // NN*64 floats

    hipMemsetAsync(agg, 0, (size_t)NN * 64 * sizeof(float), stream);
    zn_kernel<<<(NN + 255)/256, 256, 0, stream>>>(
        pos, zinc, rbf_c, rbf_w, sh_w, sh_b, zn_w, zn_b, zn_f);
    edge_kernel<<<NE/256, 256, 0, stream>>>(
        pos, ei, rbf_c, rbf_w, sh_w, sh_b, pm_w1, pm_b1, pm_w2, pm_b2, agg);
    out_kernel<<<512, 256, 0, stream>>>(
        agg, zn_f, np_w, np_b, ln_g, ln_b, out);
}

// Round 2
// 3166.056 us; speedup vs baseline: 1.8585x; 1.8585x over previous
//
#include <hip/hip_runtime.h>
#include <math.h>

#define N_BASIS 16
#define HIDDEN 64
#define OUT_DIM 128
#define NN 100000
#define NE 1600000
#define NPB 16            // nodes per gather block
#define SCAN_NB 391       // ceil(NN/256)

__device__ __forceinline__ float silu_f(float x) {
    return x / (1.0f + __expf(-x));
}

// feat[0:16] = rbf(d), feat[16:32] = sh(u) @ sh_w + sh_b
__device__ __forceinline__ void compute_feat(
    float rx, float ry, float rz,
    const float* __restrict__ sC, const float* __restrict__ sWd,
    const float* __restrict__ sShW, const float* __restrict__ sShB,
    float* feat)
{
    float d2 = rx*rx + ry*ry + rz*rz;
    float d = fmaxf(sqrtf(d2), 1e-6f);
    float inv = 1.0f / d;
    float ux = rx*inv, uy = ry*inv, uz = rz*inv;
    #pragma unroll
    for (int m = 0; m < 16; ++m) {
        float t = d - sC[m];
        feat[m] = __expf(-fabsf(sWd[m]) * t * t);
    }
    const float c0 = 0.28209479177387814f;
    const float c1 = 0.4886025119029199f;
    const float c2 = 1.0925484305920792f;
    const float c3 = 0.31539156525252005f;
    const float c4 = 0.5462742152960396f;
    float sh0 = c0;
    float sh1 = c1*uy, sh2 = c1*uz, sh3 = c1*ux;
    float sh4 = c2*ux*uy, sh5 = c2*uy*uz;
    float sh6 = c3*(2.0f*uz*uz - ux*ux - uy*uy);
    float sh7 = c2*ux*uz, sh8 = c4*(ux*ux - uy*uy);
    #pragma unroll
    for (int m = 0; m < 16; ++m) {
        float a = sShB[m];
        a += sh0*sShW[0*16+m]; a += sh1*sShW[1*16+m]; a += sh2*sShW[2*16+m];
        a += sh3*sShW[3*16+m]; a += sh4*sShW[4*16+m]; a += sh5*sShW[5*16+m];
        a += sh6*sShW[6*16+m]; a += sh7*sShW[7*16+m]; a += sh8*sShW[8*16+m];
        feat[16+m] = a;
    }
}

// ---------------- counting-sort pipeline ----------------

__global__ __launch_bounds__(256) void hist_kernel(
    const int* __restrict__ ei, int* __restrict__ count)
{
    int e = blockIdx.x * 256 + threadIdx.x;       // grid exact NE/256
    atomicAdd(&count[ei[e]], 1);
}

// in-place block-local exclusive scan of count; blocksum out
__global__ __launch_bounds__(256) void scan1_kernel(
    int* __restrict__ count, int* __restrict__ bsum)
{
    __shared__ int s[256];
    int t = threadIdx.x;
    int i = blockIdx.x * 256 + t;
    int v = (i < NN) ? count[i] : 0;
    s[t] = v;
    __syncthreads();
    #pragma unroll
    for (int off = 1; off < 256; off <<= 1) {
        int add = (t >= off) ? s[t - off] : 0;
        __syncthreads();
        s[t] += add;
        __syncthreads();
    }
    if (i < NN) count[i] = s[t] - v;              // exclusive within block
    if (t == 255) bsum[blockIdx.x] = s[255];
}

__global__ __launch_bounds__(512) void scan2_kernel(
    const int* __restrict__ bsum, int* __restrict__ bsumoff)
{
    __shared__ int s[512];
    int t = threadIdx.x;
    int v = (t < SCAN_NB) ? bsum[t] : 0;
    s[t] = v;
    __syncthreads();
    #pragma unroll
    for (int off = 1; off < 512; off <<= 1) {
        int add = (t >= off) ? s[t - off] : 0;
        __syncthreads();
        s[t] += add;
        __syncthreads();
    }
    if (t < SCAN_NB) bsumoff[t] = s[t] - v;       // exclusive
}

__global__ __launch_bounds__(256) void scan3_kernel(
    const int* __restrict__ count, const int* __restrict__ bsumoff,
    int* __restrict__ start, int* __restrict__ cursor)
{
    int i = blockIdx.x * 256 + threadIdx.x;
    if (i < NN) {
        int v = count[i] + bsumoff[blockIdx.x];
        start[i] = v;
        cursor[i] = v;
    }
    if (i == 0) start[NN] = NE;
}

__global__ __launch_bounds__(256) void scatter_kernel(
    const int* __restrict__ ei, int* __restrict__ cursor,
    int* __restrict__ sdst)
{
    int e = blockIdx.x * 256 + threadIdx.x;
    int s = ei[e], d = ei[NE + e];
    int p = atomicAdd(&cursor[s], 1);
    sdst[p] = d;
}

// ---------------- gather: per-edge MLP + LDS tile reduction ----------------

__global__ __launch_bounds__(256) void gather_kernel(
    const float* __restrict__ pos, const int* __restrict__ sdst,
    const int* __restrict__ start,
    const float* __restrict__ rbf_c, const float* __restrict__ rbf_w,
    const float* __restrict__ sh_w, const float* __restrict__ sh_b,
    const float* __restrict__ w1, const float* __restrict__ b1,
    const float* __restrict__ w2, const float* __restrict__ b2,
    float* __restrict__ agg)
{
    __shared__ float sW1[2048];
    __shared__ float sW2[4096];
    __shared__ float tile[NPB * 64];
    __shared__ float sShW[144], sShB[16], sC[16], sWd[16], sB1[64], sB2[64];
    __shared__ int sStart[NPB + 1];
    int tid = threadIdx.x;
    int nlo = blockIdx.x * NPB;
    for (int i = tid; i < 2048; i += 256) sW1[i] = w1[i];
    for (int i = tid; i < 4096; i += 256) sW2[i] = w2[i];
    for (int i = tid; i < NPB * 64; i += 256) tile[i] = 0.0f;
    if (tid < 144) sShW[tid] = sh_w[tid];
    if (tid < 16) { sShB[tid] = sh_b[tid]; sC[tid] = rbf_c[tid]; sWd[tid] = rbf_w[tid]; }
    if (tid < 64) sB1[tid] = b1[tid];
    if (tid >= 64 && tid < 128) sB2[tid-64] = b2[tid-64];
    if (tid >= 128 && tid < 128 + NPB + 1) sStart[tid-128] = start[nlo + tid - 128];
    __syncthreads();

    int pbeg = sStart[0], pend = sStart[NPB];
    // preload local pos for the 16 owned nodes into registers? cheap enough via LDS:
    __shared__ float sPosL[NPB * 3];
    if (tid < NPB * 3) sPosL[tid] = pos[(size_t)nlo * 3 + tid];
    __syncthreads();

    for (int p = pbeg + tid; p < pend; p += 256) {
        // recover local src index: sStart[j] <= p < sStart[j+1]
        int j = 0;
        #pragma unroll
        for (int k = 1; k < NPB; ++k) j += (p >= sStart[k]);
        int d = sdst[p];
        float rx = pos[(size_t)d*3+0] - sPosL[j*3+0];
        float ry = pos[(size_t)d*3+1] - sPosL[j*3+1];
        float rz = pos[(size_t)d*3+2] - sPosL[j*3+2];
        float feat[32];
        compute_feat(rx, ry, rz, sC, sWd, sShW, sShB, feat);

        float h2[64];
        #pragma unroll
        for (int o = 0; o < 64; ++o) h2[o] = sB2[o];

        #pragma unroll 1
        for (int jc = 0; jc < 8; ++jc) {
            float h1c[8];
            #pragma unroll
            for (int jj = 0; jj < 8; ++jj) h1c[jj] = sB1[jc*8+jj];
            #pragma unroll
            for (int k = 0; k < 32; ++k) {
                float f = feat[k];
                #pragma unroll
                for (int jj = 0; jj < 8; ++jj) h1c[jj] += f * sW1[k*64 + jc*8 + jj];
            }
            #pragma unroll
            for (int jj = 0; jj < 8; ++jj) h1c[jj] = silu_f(h1c[jj]);
            #pragma unroll
            for (int jj = 0; jj < 8; ++jj) {
                float v = h1c[jj];
                #pragma unroll
                for (int o = 0; o < 64; ++o) h2[o] += v * sW2[(jc*8+jj)*64 + o];
            }
        }
        float* trow = &tile[j * 64];
        #pragma unroll
        for (int o = 0; o < 64; ++o) atomicAdd(&trow[o], h2[o]);
    }
    __syncthreads();
    for (int i = tid; i < NPB * 64; i += 256)
        agg[(size_t)nlo * 64 + i] = tile[i];
}

// ---------------- fallback (round-1) atomic edge kernel ----------------

__global__ __launch_bounds__(256) void edge_kernel(
    const float* __restrict__ pos, const int* __restrict__ edge_index,
    const float* __restrict__ rbf_c, const float* __restrict__ rbf_w,
    const float* __restrict__ sh_w, const float* __restrict__ sh_b,
    const float* __restrict__ w1, const float* __restrict__ b1,
    const float* __restrict__ w2, const float* __restrict__ b2,
    float* __restrict__ agg)
{
    __shared__ float sW1[2048];
    __shared__ float sW2[4096];
    __shared__ float sShW[144], sShB[16], sC[16], sWd[16], sB1[64], sB2[64];
    int tid = threadIdx.x;
    for (int i = tid; i < 2048; i += 256) sW1[i] = w1[i];
    for (int i = tid; i < 4096; i += 256) sW2[i] = w2[i];
    if (tid < 144) sShW[tid] = sh_w[tid];
    if (tid < 16) { sShB[tid] = sh_b[tid]; sC[tid] = rbf_c[tid]; sWd[tid] = rbf_w[tid]; }
    if (tid < 64) sB1[tid] = b1[tid];
    if (tid >= 64 && tid < 128) sB2[tid-64] = b2[tid-64];
    __syncthreads();

    int e = blockIdx.x * 256 + tid;
    int s   = edge_index[e];
    int dst = edge_index[NE + e];
    const float* ps = pos + 3*(size_t)s;
    const float* pd = pos + 3*(size_t)dst;
    float rx = pd[0]-ps[0], ry = pd[1]-ps[1], rz = pd[2]-ps[2];
    float feat[32];
    compute_feat(rx, ry, rz, sC, sWd, sShW, sShB, feat);

    float h2[64];
    #pragma unroll
    for (int o = 0; o < 64; ++o) h2[o] = sB2[o];

    #pragma unroll 1
    for (int jc = 0; jc < 8; ++jc) {
        float h1c[8];
        #pragma unroll
        for (int jj = 0; jj < 8; ++jj) h1c[jj] = sB1[jc*8+jj];
        #pragma unroll
        for (int k = 0; k < 32; ++k) {
            float f = feat[k];
            #pragma unroll
            for (int jj = 0; jj < 8; ++jj) h1c[jj] += f * sW1[k*64 + jc*8 + jj];
        }
        #pragma unroll
        for (int jj = 0; jj < 8; ++jj) h1c[jj] = silu_f(h1c[jj]);
        #pragma unroll
        for (int jj = 0; jj < 8; ++jj) {
            float v = h1c[jj];
            #pragma unroll
            for (int o = 0; o < 64; ++o) h2[o] += v * sW2[(jc*8+jj)*64 + o];
        }
    }
    size_t base = (size_t)s * 64;
    #pragma unroll
    for (int o = 0; o < 64; ++o)
        unsafeAtomicAdd(&agg[base + o], h2[o]);
}

// ---------------- zinc branch ----------------

__global__ __launch_bounds__(256) void zn_kernel(
    const float* __restrict__ pos, const float* __restrict__ zinc_pos,
    const float* __restrict__ rbf_c, const float* __restrict__ rbf_w,
    const float* __restrict__ sh_w, const float* __restrict__ sh_b,
    const float* __restrict__ zn_w, const float* __restrict__ zn_b,
    float* __restrict__ zn_f)
{
    __shared__ float sW[2048];
    __shared__ float sShW[144], sShB[16], sC[16], sWd[16], sB[64];
    int tid = threadIdx.x;
    for (int i = tid; i < 2048; i += 256) sW[i] = zn_w[i];
    if (tid < 144) sShW[tid] = sh_w[tid];
    if (tid < 16) { sShB[tid] = sh_b[tid]; sC[tid] = rbf_c[tid]; sWd[tid] = rbf_w[tid]; }
    if (tid < 64) sB[tid] = zn_b[tid];
    __syncthreads();
    int n = blockIdx.x * 256 + tid;
    if (n >= NN) return;
    float rx = pos[n*3+0] - zinc_pos[0];
    float ry = pos[n*3+1] - zinc_pos[1];
    float rz = pos[n*3+2] - zinc_pos[2];
    float feat[32];
    compute_feat(rx, ry, rz, sC, sWd, sShW, sShB, feat);
    #pragma unroll 1
    for (int jc = 0; jc < 8; ++jc) {
        float h[8];
        #pragma unroll
        for (int jj = 0; jj < 8; ++jj) h[jj] = sB[jc*8+jj];
        #pragma unroll
        for (int k = 0; k < 32; ++k) {
            float f = feat[k];
            #pragma unroll
            for (int jj = 0; jj < 8; ++jj) h[jj] += f * sW[k*64 + jc*8 + jj];
        }
        #pragma unroll
        for (int jj = 0; jj < 8; ++jj)
            zn_f[(size_t)n*64 + jc*8 + jj] = silu_f(h[jj]);
    }
}

// ---------------- output projection + LN + SiLU ----------------

__global__ __launch_bounds__(256) void out_kernel(
    const float* __restrict__ agg, const float* __restrict__ zn_f,
    const float* __restrict__ np_w, const float* __restrict__ np_b,
    const float* __restrict__ ln_g, const float* __restrict__ ln_b,
    float* __restrict__ out)
{
    __shared__ float sX[128*36];
    __shared__ float sH[32*130];
    __shared__ float sMu[32], sVar[32];
    int tid = threadIdx.x;
    int o = tid & 127;
    int nb = (tid >> 7) * 16;
    float bias = np_b[o];
    float g = ln_g[o], bta = ln_b[o];

    for (int n0 = blockIdx.x * 32; n0 < NN; n0 += gridDim.x * 32) {
        for (int i = tid; i < 4096; i += 256) {
            int n = i >> 7, k = i & 127;
            float v = (k < 64) ? agg[(size_t)(n0+n)*64 + k]
                               : zn_f[(size_t)(n0+n)*64 + (k-64)];
            sX[k*36 + n] = v;
        }
        __syncthreads();
        float acc[16];
        #pragma unroll
        for (int i = 0; i < 16; ++i) acc[i] = bias;
        #pragma unroll 4
        for (int k = 0; k < 128; ++k) {
            float w = np_w[k*128 + o];
            const float* xr = &sX[k*36 + nb];
            #pragma unroll
            for (int i = 0; i < 16; ++i) acc[i] += w * xr[i];
        }
        #pragma unroll
        for (int i = 0; i < 16; ++i) sH[(nb+i)*130 + o] = acc[i];
        __syncthreads();
        if (tid < 32) {
            float s = 0.0f, sq = 0.0f;
            for (int oo = 0; oo < 128; ++oo) {
                float v = sH[tid*130 + oo];
                s += v; sq += v*v;
            }
            float mu = s * (1.0f/128.0f);
            sMu[tid] = mu;
            sVar[tid] = sq * (1.0f/128.0f) - mu*mu;
        }
        __syncthreads();
        #pragma unroll
        for (int i = 0; i < 16; ++i) {
            int n = nb + i;
            float y = (acc[i] - sMu[n]) * rsqrtf(sVar[n] + 1e-5f) * g + bta;
            out[(size_t)(n0+n)*128 + o] = silu_f(y);
        }
        __syncthreads();
    }
}

extern "C" void kernel_launch(void* const* d_in, const int* in_sizes, int n_in,
                              void* d_out, int out_size, void* d_ws, size_t ws_size,
                              hipStream_t stream) {
    const float* pos   = (const float*)d_in[0];
    const float* zinc  = (const float*)d_in[1];
    const int*   ei    = (const int*)  d_in[2];
    const float* rbf_c = (const float*)d_in[3];
    const float* rbf_w = (const float*)d_in[4];
    const float* sh_w  = (const float*)d_in[5];
    const float* sh_b  = (const float*)d_in[6];
    const float* pm_w1 = (const float*)d_in[7];
    const float* pm_b1 = (const float*)d_in[8];
    const float* pm_w2 = (const float*)d_in[9];
    const float* pm_b2 = (const float*)d_in[10];
    const float* zn_w  = (const float*)d_in[11];
    const float* zn_b  = (const float*)d_in[12];
    const float* np_w  = (const float*)d_in[13];
    const float* np_b  = (const float*)d_in[14];
    const float* ln_g  = (const float*)d_in[15];
    const float* ln_b  = (const float*)d_in[16];
    float* out  = (float*)d_out;

    float* agg  = (float*)d_ws;                        // NN*64 f
    float* zn_f = agg + (size_t)NN * 64;               // NN*64 f
    int* count   = (int*)(zn_f + (size_t)NN * 64);     // NN
    int* start   = count + NN;                         // NN+1
    int* cursor  = start + NN + 1;                     // NN
    int* bsum    = cursor + NN;                        // 512
    int* bsumoff = bsum + 512;                         // 512
    int* sdst    = bsumoff + 512;                      // NE
    size_t needed = (size_t)((char*)(sdst + NE) - (char*)d_ws);

    zn_kernel<<<(NN + 255)/256, 256, 0, stream>>>(
        pos, zinc, rbf_c, rbf_w, sh_w, sh_b, zn_w, zn_b, zn_f);

    if (ws_size >= needed) {
        // counting sort by src, then atomic-free gather
        hipMemsetAsync(count, 0, NN * sizeof(int), stream);
        hist_kernel<<<NE/256, 256, 0, stream>>>(ei, count);
        scan1_kernel<<<SCAN_NB, 256, 0, stream>>>(count, bsum);
        scan2_kernel<<<1, 512, 0, stream>>>(bsum, bsumoff);
        scan3_kernel<<<SCAN_NB, 256, 0, stream>>>(count, bsumoff, start, cursor);
        scatter_kernel<<<NE/256, 256, 0, stream>>>(ei, cursor, sdst);
        gather_kernel<<<NN/NPB, 256, 0, stream>>>(
            pos, sdst, start, rbf_c, rbf_w, sh_w, sh_b,
            pm_w1, pm_b1, pm_w2, pm_b2, agg);
    } else {
        // fallback: global-atomic path
        hipMemsetAsync(agg, 0, (size_t)NN * 64 * sizeof(float), stream);
        edge_kernel<<<NE/256, 256, 0, stream>>>(
            pos, ei, rbf_c, rbf_w, sh_w, sh_b, pm_w1, pm_b1, pm_w2, pm_b2, agg);
    }

    out_kernel<<<512, 256, 0, stream>>>(
        agg, zn_f, np_w, np_b, ln_g, ln_b, out);
}

// Round 3
// 1226.413 us; speedup vs baseline: 4.7978x; 2.5816x over previous
//
#include <hip/hip_runtime.h>
#include <math.h>

#define N_BASIS 16
#define HIDDEN 64
#define OUT_DIM 128
#define NN 100000
#define NE 1600000
#define NPB 16            // nodes per gather block
#define SCAN_NB 391       // ceil(NN/256)

typedef __bf16 bfrag __attribute__((ext_vector_type(8)));
typedef float  ffrag __attribute__((ext_vector_type(4)));

union BF8 { bfrag v; uint4 u4; uint2 u2[2]; };

__device__ __forceinline__ unsigned pack_bf2(float lo, float hi) {
    union { float f; unsigned u; } a, b;
    a.f = lo; b.f = hi;
    unsigned ra = a.u + 0x7FFFu + ((a.u >> 16) & 1u);
    unsigned rb = b.u + 0x7FFFu + ((b.u >> 16) & 1u);
    return (ra >> 16) | (rb & 0xFFFF0000u);
}

__device__ __forceinline__ float silu_f(float x) {
    return x / (1.0f + __expf(-x));
}

// Old-style feat (zn + fallback): rbf(16) + sh@sh_w+sh_b (16)
__device__ __forceinline__ void compute_feat(
    float rx, float ry, float rz,
    const float* __restrict__ sC, const float* __restrict__ sWd,
    const float* __restrict__ sShW, const float* __restrict__ sShB,
    float* feat)
{
    float d2 = rx*rx + ry*ry + rz*rz;
    float d = fmaxf(sqrtf(d2), 1e-6f);
    float inv = 1.0f / d;
    float ux = rx*inv, uy = ry*inv, uz = rz*inv;
    #pragma unroll
    for (int m = 0; m < 16; ++m) {
        float t = d - sC[m];
        feat[m] = __expf(-fabsf(sWd[m]) * t * t);
    }
    const float c0 = 0.28209479177387814f;
    const float c1 = 0.4886025119029199f;
    const float c2 = 1.0925484305920792f;
    const float c3 = 0.31539156525252005f;
    const float c4 = 0.5462742152960396f;
    float sh0 = c0;
    float sh1 = c1*uy, sh2 = c1*uz, sh3 = c1*ux;
    float sh4 = c2*ux*uy, sh5 = c2*uy*uz;
    float sh6 = c3*(2.0f*uz*uz - ux*ux - uy*uy);
    float sh7 = c2*ux*uz, sh8 = c4*(ux*ux - uy*uy);
    #pragma unroll
    for (int m = 0; m < 16; ++m) {
        float a = sShB[m];
        a += sh0*sShW[0*16+m]; a += sh1*sShW[1*16+m]; a += sh2*sShW[2*16+m];
        a += sh3*sShW[3*16+m]; a += sh4*sShW[4*16+m]; a += sh5*sShW[5*16+m];
        a += sh6*sShW[6*16+m]; a += sh7*sShW[7*16+m]; a += sh8*sShW[8*16+m];
        feat[16+m] = a;
    }
}

// Folded feat for MFMA path: rbf(16) + raw SH basis(9) + 7 zeros (K=32)
__device__ __forceinline__ void compute_feat2(
    float rx, float ry, float rz,
    const float* __restrict__ rbf_c, const float* __restrict__ rbf_w,
    float* feat)
{
    float d2 = rx*rx + ry*ry + rz*rz;
    float d = fmaxf(sqrtf(d2), 1e-6f);
    float inv = 1.0f / d;
    float ux = rx*inv, uy = ry*inv, uz = rz*inv;
    #pragma unroll
    for (int m = 0; m < 16; ++m) {
        float t = d - rbf_c[m];          // uniform -> s_load
        feat[m] = __expf(-fabsf(rbf_w[m]) * t * t);
    }
    const float c0 = 0.28209479177387814f;
    const float c1 = 0.4886025119029199f;
    const float c2 = 1.0925484305920792f;
    const float c3 = 0.31539156525252005f;
    const float c4 = 0.5462742152960396f;
    feat[16] = c0;
    feat[17] = c1*uy; feat[18] = c1*uz; feat[19] = c1*ux;
    feat[20] = c2*ux*uy; feat[21] = c2*uy*uz;
    feat[22] = c3*(2.0f*uz*uz - ux*ux - uy*uy);
    feat[23] = c2*ux*uz; feat[24] = c4*(ux*ux - uy*uy);
    #pragma unroll
    for (int m = 25; m < 32; ++m) feat[m] = 0.0f;
}

// Fold sh_w/sh_b into W1/b1: W1eff[32][64], b1eff[64]
__global__ __launch_bounds__(64) void prep_kernel(
    const float* __restrict__ sh_w, const float* __restrict__ sh_b,
    const float* __restrict__ w1, const float* __restrict__ b1,
    float* __restrict__ w1e, float* __restrict__ b1e)
{
    int j = threadIdx.x;
    #pragma unroll
    for (int k = 0; k < 16; ++k) w1e[k*64 + j] = w1[k*64 + j];
    for (int s = 0; s < 9; ++s) {
        float a = 0.0f;
        for (int m = 0; m < 16; ++m) a += sh_w[s*16 + m] * w1[(16+m)*64 + j];
        w1e[(16+s)*64 + j] = a;
    }
    #pragma unroll
    for (int s = 25; s < 32; ++s) w1e[s*64 + j] = 0.0f;
    float bb = b1[j];
    for (int m = 0; m < 16; ++m) bb += sh_b[m] * w1[(16+m)*64 + j];
    b1e[j] = bb;
}

// ---------------- counting-sort pipeline ----------------

__global__ __launch_bounds__(256) void hist_kernel(
    const int* __restrict__ ei, int* __restrict__ count)
{
    int e = blockIdx.x * 256 + threadIdx.x;
    atomicAdd(&count[ei[e]], 1);
}

__global__ __launch_bounds__(256) void scan1_kernel(
    int* __restrict__ count, int* __restrict__ bsum)
{
    __shared__ int s[256];
    int t = threadIdx.x;
    int i = blockIdx.x * 256 + t;
    int v = (i < NN) ? count[i] : 0;
    s[t] = v;
    __syncthreads();
    #pragma unroll
    for (int off = 1; off < 256; off <<= 1) {
        int add = (t >= off) ? s[t - off] : 0;
        __syncthreads();
        s[t] += add;
        __syncthreads();
    }
    if (i < NN) count[i] = s[t] - v;
    if (t == 255) bsum[blockIdx.x] = s[255];
}

__global__ __launch_bounds__(512) void scan2_kernel(
    const int* __restrict__ bsum, int* __restrict__ bsumoff)
{
    __shared__ int s[512];
    int t = threadIdx.x;
    int v = (t < SCAN_NB) ? bsum[t] : 0;
    s[t] = v;
    __syncthreads();
    #pragma unroll
    for (int off = 1; off < 512; off <<= 1) {
        int add = (t >= off) ? s[t - off] : 0;
        __syncthreads();
        s[t] += add;
        __syncthreads();
    }
    if (t < SCAN_NB) bsumoff[t] = s[t] - v;
}

__global__ __launch_bounds__(256) void scan3_kernel(
    const int* __restrict__ count, const int* __restrict__ bsumoff,
    int* __restrict__ start, int* __restrict__ cursor)
{
    int i = blockIdx.x * 256 + threadIdx.x;
    if (i < NN) {
        int v = count[i] + bsumoff[blockIdx.x];
        start[i] = v;
        cursor[i] = v;
    }
    if (i == 0) start[NN] = NE;
}

// sdj[p] = (dst<<4) | (src & 15)  -- src's local index within its 16-node block
__global__ __launch_bounds__(256) void scatter_kernel(
    const int* __restrict__ ei, int* __restrict__ cursor,
    int* __restrict__ sdj)
{
    int e = blockIdx.x * 256 + threadIdx.x;
    int s = ei[e], d = ei[NE + e];
    int p = atomicAdd(&cursor[s], 1);
    sdj[p] = (d << 4) | (s & 15);
}

// ---------------- MFMA gather ----------------
// Per wave, 64 sorted edges/batch:
//   H1^T(64j x 64e) = W1eff^T @ FEAT^T  (16 mfma_16x16x32_bf16, W1 in regs)
//   P = silu(H1) -> LDS (bf16)
//   H2^T(64o x 64e) = W2^T @ P^T        (32 mfma, W2 in regs)
//   LDS-atomic into 16x64 node tile, one coalesced store at end.
__global__ __launch_bounds__(256) void gather_mfma_kernel(
    const float* __restrict__ pos,
    const int* __restrict__ sdj, const int* __restrict__ start,
    const float* __restrict__ rbf_c, const float* __restrict__ rbf_w,
    const float* __restrict__ w1e, const float* __restrict__ b1e,
    const float* __restrict__ w2, const float* __restrict__ b2,
    float* __restrict__ agg)
{
    // featB: [wave][64 edges][20 uints (32 bf16 + pad)]  stride 80B (16B-mult, bank-spread)
    // h1t:   [wave][16 edges][34 uints (64 bf16 + pad)]  stride 136B (8B-mult, <=4-way banks)
    __shared__ unsigned featB[4 * 64 * 20];
    __shared__ unsigned h1t[4 * 16 * 34];
    __shared__ float tile[NPB * 64];
    __shared__ float sPosL[NPB * 3];

    int tid = threadIdx.x;
    int wave = tid >> 6, lane = tid & 63;
    int lm = lane & 15, q = lane >> 4;
    int nlo = blockIdx.x * NPB;

    for (int i = tid; i < NPB * 64; i += 256) tile[i] = 0.0f;
    if (tid < NPB * 3) sPosL[tid] = pos[(size_t)nlo * 3 + tid];
    __syncthreads();

    // Register-resident weight fragments (A-operands, loaded once per wave)
    bfrag w1f[4];
    #pragma unroll
    for (int mt = 0; mt < 4; ++mt)
        #pragma unroll
        for (int kk = 0; kk < 8; ++kk)
            w1f[mt][kk] = (__bf16)w1e[(q*8 + kk)*64 + mt*16 + lm];
    bfrag w2f[2][4];
    #pragma unroll
    for (int kb = 0; kb < 2; ++kb)
        #pragma unroll
        for (int mt = 0; mt < 4; ++mt)
            #pragma unroll
            for (int kk = 0; kk < 8; ++kk)
                w2f[kb][mt][kk] = (__bf16)w2[(kb*32 + q*8 + kk)*64 + mt*16 + lm];
    ffrag b1v[4], b2v[4];
    #pragma unroll
    for (int mt = 0; mt < 4; ++mt)
        #pragma unroll
        for (int r = 0; r < 4; ++r) {
            b1v[mt][r] = b1e[mt*16 + q*4 + r];
            b2v[mt][r] = b2[mt*16 + q*4 + r];
        }

    int pbeg = start[nlo], pend = start[nlo + NPB];
    unsigned* fW = &featB[wave * 64 * 20];
    unsigned* hW = &h1t[wave * 16 * 34];

    for (int pb = pbeg + wave * 64; pb < pend; pb += 256) {
        int p = pb + lane;
        int pc = (p < pend) ? p : (pend - 1);
        int v  = sdj[pc];
        int d  = v >> 4;
        int jn = v & 15;
        float rx = pos[(size_t)d*3+0] - sPosL[jn*3+0];
        float ry = pos[(size_t)d*3+1] - sPosL[jn*3+1];
        float rz = pos[(size_t)d*3+2] - sPosL[jn*3+2];
        float feat[32];
        compute_feat2(rx, ry, rz, rbf_c, rbf_w, feat);
        #pragma unroll
        for (int c = 0; c < 4; ++c) {
            uint4 w;
            w.x = pack_bf2(feat[c*8+0], feat[c*8+1]);
            w.y = pack_bf2(feat[c*8+2], feat[c*8+3]);
            w.z = pack_bf2(feat[c*8+4], feat[c*8+5]);
            w.w = pack_bf2(feat[c*8+6], feat[c*8+7]);
        *(uint4*)&fW[lane*20 + c*4] = w;
        }

        #pragma unroll
        for (int nt = 0; nt < 4; ++nt) {
            BF8 bf;
            bf.u4 = *(const uint4*)&fW[(nt*16 + lm)*20 + q*4];
            ffrag a1[4];
            #pragma unroll
            for (int mt = 0; mt < 4; ++mt) a1[mt] = b1v[mt];
            #pragma unroll
            for (int mt = 0; mt < 4; ++mt)
                a1[mt] = __builtin_amdgcn_mfma_f32_16x16x32_bf16(w1f[mt], bf.v, a1[mt], 0, 0, 0);
            // silu -> bf16 -> LDS (row = lm-edge, cols = 4 consecutive j)
            #pragma unroll
            for (int mt = 0; mt < 4; ++mt) {
                float s0 = silu_f(a1[mt][0]);
                float s1 = silu_f(a1[mt][1]);
                float s2 = silu_f(a1[mt][2]);
                float s3 = silu_f(a1[mt][3]);
                uint2 w;
                w.x = pack_bf2(s0, s1);
                w.y = pack_bf2(s2, s3);
                *(uint2*)&hW[lm*34 + mt*8 + q*2] = w;
            }
            ffrag a2[4];
            #pragma unroll
            for (int mt = 0; mt < 4; ++mt) a2[mt] = b2v[mt];
            #pragma unroll
            for (int kb = 0; kb < 2; ++kb) {
                BF8 pf;
                pf.u2[0] = *(const uint2*)&hW[lm*34 + kb*16 + q*4];
                pf.u2[1] = *(const uint2*)&hW[lm*34 + kb*16 + q*4 + 2];
                #pragma unroll
                for (int mt = 0; mt < 4; ++mt)
                    a2[mt] = __builtin_amdgcn_mfma_f32_16x16x32_bf16(w2f[kb][mt], pf.v, a2[mt], 0, 0, 0);
            }
            int pe = pb + nt*16 + lm;
            if (pe < pend) {
                int je = sdj[pe] & 15;
                float* trow = &tile[je * 64];
                #pragma unroll
                for (int mt = 0; mt < 4; ++mt)
                    #pragma unroll
                    for (int r = 0; r < 4; ++r)
                        atomicAdd(&trow[mt*16 + q*4 + r], a2[mt][r]);
            }
        }
    }
    __syncthreads();
    for (int i = tid; i < NPB * 64; i += 256)
        agg[(size_t)nlo * 64 + i] = tile[i];
}

// ---------------- fallback (round-1) atomic edge kernel ----------------

__global__ __launch_bounds__(256) void edge_kernel(
    const float* __restrict__ pos, const int* __restrict__ edge_index,
    const float* __restrict__ rbf_c, const float* __restrict__ rbf_w,
    const float* __restrict__ sh_w, const float* __restrict__ sh_b,
    const float* __restrict__ w1, const float* __restrict__ b1,
    const float* __restrict__ w2, const float* __restrict__ b2,
    float* __restrict__ agg)
{
    __shared__ float sW1[2048];
    __shared__ float sW2[4096];
    __shared__ float sShW[144], sShB[16], sC[16], sWd[16], sB1[64], sB2[64];
    int tid = threadIdx.x;
    for (int i = tid; i < 2048; i += 256) sW1[i] = w1[i];
    for (int i = tid; i < 4096; i += 256) sW2[i] = w2[i];
    if (tid < 144) sShW[tid] = sh_w[tid];
    if (tid < 16) { sShB[tid] = sh_b[tid]; sC[tid] = rbf_c[tid]; sWd[tid] = rbf_w[tid]; }
    if (tid < 64) sB1[tid] = b1[tid];
    if (tid >= 64 && tid < 128) sB2[tid-64] = b2[tid-64];
    __syncthreads();

    int e = blockIdx.x * 256 + tid;
    int s   = edge_index[e];
    int dst = edge_index[NE + e];
    const float* ps = pos + 3*(size_t)s;
    const float* pd = pos + 3*(size_t)dst;
    float rx = pd[0]-ps[0], ry = pd[1]-ps[1], rz = pd[2]-ps[2];
    float feat[32];
    compute_feat(rx, ry, rz, sC, sWd, sShW, sShB, feat);

    float h2[64];
    #pragma unroll
    for (int o = 0; o < 64; ++o) h2[o] = sB2[o];

    #pragma unroll 1
    for (int jc = 0; jc < 8; ++jc) {
        float h1c[8];
        #pragma unroll
        for (int jj = 0; jj < 8; ++jj) h1c[jj] = sB1[jc*8+jj];
        #pragma unroll
        for (int k = 0; k < 32; ++k) {
            float f = feat[k];
            #pragma unroll
            for (int jj = 0; jj < 8; ++jj) h1c[jj] += f * sW1[k*64 + jc*8 + jj];
        }
        #pragma unroll
        for (int jj = 0; jj < 8; ++jj) h1c[jj] = silu_f(h1c[jj]);
        #pragma unroll
        for (int jj = 0; jj < 8; ++jj) {
            float v = h1c[jj];
            #pragma unroll
            for (int o = 0; o < 64; ++o) h2[o] += v * sW2[(jc*8+jj)*64 + o];
        }
    }
    size_t base = (size_t)s * 64;
    #pragma unroll
    for (int o = 0; o < 64; ++o)
        unsafeAtomicAdd(&agg[base + o], h2[o]);
}

// ---------------- zinc branch ----------------

__global__ __launch_bounds__(256) void zn_kernel(
    const float* __restrict__ pos, const float* __restrict__ zinc_pos,
    const float* __restrict__ rbf_c, const float* __restrict__ rbf_w,
    const float* __restrict__ sh_w, const float* __restrict__ sh_b,
    const float* __restrict__ zn_w, const float* __restrict__ zn_b,
    float* __restrict__ zn_f)
{
    __shared__ float sW[2048];
    __shared__ float sShW[144], sShB[16], sC[16], sWd[16], sB[64];
    int tid = threadIdx.x;
    for (int i = tid; i < 2048; i += 256) sW[i] = zn_w[i];
    if (tid < 144) sShW[tid] = sh_w[tid];
    if (tid < 16) { sShB[tid] = sh_b[tid]; sC[tid] = rbf_c[tid]; sWd[tid] = rbf_w[tid]; }
    if (tid < 64) sB[tid] = zn_b[tid];
    __syncthreads();
    int n = blockIdx.x * 256 + tid;
    if (n >= NN) return;
    float rx = pos[n*3+0] - zinc_pos[0];
    float ry = pos[n*3+1] - zinc_pos[1];
    float rz = pos[n*3+2] - zinc_pos[2];
    float feat[32];
    compute_feat(rx, ry, rz, sC, sWd, sShW, sShB, feat);
    #pragma unroll 1
    for (int jc = 0; jc < 8; ++jc) {
        float h[8];
        #pragma unroll
        for (int jj = 0; jj < 8; ++jj) h[jj] = sB[jc*8+jj];
        #pragma unroll
        for (int k = 0; k < 32; ++k) {
            float f = feat[k];
            #pragma unroll
            for (int jj = 0; jj < 8; ++jj) h[jj] += f * sW[k*64 + jc*8 + jj];
        }
        #pragma unroll
        for (int jj = 0; jj < 8; ++jj)
            zn_f[(size_t)n*64 + jc*8 + jj] = silu_f(h[jj]);
    }
}

// ---------------- output projection + LN + SiLU ----------------

__global__ __launch_bounds__(256) void out_kernel(
    const float* __restrict__ agg, const float* __restrict__ zn_f,
    const float* __restrict__ np_w, const float* __restrict__ np_b,
    const float* __restrict__ ln_g, const float* __restrict__ ln_b,
    float* __restrict__ out)
{
    __shared__ float sX[128*36];
    __shared__ float sH[32*130];
    __shared__ float sMu[32], sVar[32];
    int tid = threadIdx.x;
    int o = tid & 127;
    int nb = (tid >> 7) * 16;
    float bias = np_b[o];
    float g = ln_g[o], bta = ln_b[o];

    for (int n0 = blockIdx.x * 32; n0 < NN; n0 += gridDim.x * 32) {
        for (int i = tid; i < 4096; i += 256) {
            int n = i >> 7, k = i & 127;
            float v = (k < 64) ? agg[(size_t)(n0+n)*64 + k]
                               : zn_f[(size_t)(n0+n)*64 + (k-64)];
            sX[k*36 + n] = v;
        }
        __syncthreads();
        float acc[16];
        #pragma unroll
        for (int i = 0; i < 16; ++i) acc[i] = bias;
        #pragma unroll 4
        for (int k = 0; k < 128; ++k) {
            float w = np_w[k*128 + o];
            const float* xr = &sX[k*36 + nb];
            #pragma unroll
            for (int i = 0; i < 16; ++i) acc[i] += w * xr[i];
        }
        #pragma unroll
        for (int i = 0; i < 16; ++i) sH[(nb+i)*130 + o] = acc[i];
        __syncthreads();
        if (tid < 32) {
            float s = 0.0f, sq = 0.0f;
            for (int oo = 0; oo < 128; ++oo) {
                float v = sH[tid*130 + oo];
                s += v; sq += v*v;
            }
            float mu = s * (1.0f/128.0f);
            sMu[tid] = mu;
            sVar[tid] = sq * (1.0f/128.0f) - mu*mu;
        }
        __syncthreads();
        #pragma unroll
        for (int i = 0; i < 16; ++i) {
            int n = nb + i;
            float y = (acc[i] - sMu[n]) * rsqrtf(sVar[n] + 1e-5f) * g + bta;
            out[(size_t)(n0+n)*128 + o] = silu_f(y);
        }
        __syncthreads();
    }
}

extern "C" void kernel_launch(void* const* d_in, const int* in_sizes, int n_in,
                              void* d_out, int out_size, void* d_ws, size_t ws_size,
                              hipStream_t stream) {
    const float* pos   = (const float*)d_in[0];
    const float* zinc  = (const float*)d_in[1];
    const int*   ei    = (const int*)  d_in[2];
    const float* rbf_c = (const float*)d_in[3];
    const float* rbf_w = (const float*)d_in[4];
    const float* sh_w  = (const float*)d_in[5];
    const float* sh_b  = (const float*)d_in[6];
    const float* pm_w1 = (const float*)d_in[7];
    const float* pm_b1 = (const float*)d_in[8];
    const float* pm_w2 = (const float*)d_in[9];
    const float* pm_b2 = (const float*)d_in[10];
    const float* zn_w  = (const float*)d_in[11];
    const float* zn_b  = (const float*)d_in[12];
    const float* np_w  = (const float*)d_in[13];
    const float* np_b  = (const float*)d_in[14];
    const float* ln_g  = (const float*)d_in[15];
    const float* ln_b  = (const float*)d_in[16];
    float* out  = (float*)d_out;

    float* agg  = (float*)d_ws;                        // NN*64 f
    float* zn_f = agg + (size_t)NN * 64;               // NN*64 f
    int* count   = (int*)(zn_f + (size_t)NN * 64);     // NN
    int* start   = count + NN;                         // NN+1
    int* cursor  = start + NN + 1;                     // NN
    int* bsum    = cursor + NN;                        // 512
    int* bsumoff = bsum + 512;                         // 512
    int* sdj     = bsumoff + 512;                      // NE
    float* w1e   = (float*)(sdj + NE);                 // 2048
    float* b1e   = w1e + 2048;                         // 64
    size_t needed = (size_t)((char*)(b1e + 64) - (char*)d_ws);

    zn_kernel<<<(NN + 255)/256, 256, 0, stream>>>(
        pos, zinc, rbf_c, rbf_w, sh_w, sh_b, zn_w, zn_b, zn_f);

    if (ws_size >= needed) {
        hipMemsetAsync(count, 0, NN * sizeof(int), stream);
        hist_kernel<<<NE/256, 256, 0, stream>>>(ei, count);
        scan1_kernel<<<SCAN_NB, 256, 0, stream>>>(count, bsum);
        scan2_kernel<<<1, 512, 0, stream>>>(bsum, bsumoff);
        scan3_kernel<<<SCAN_NB, 256, 0, stream>>>(count, bsumoff, start, cursor);
        scatter_kernel<<<NE/256, 256, 0, stream>>>(ei, cursor, sdj);
        prep_kernel<<<1, 64, 0, stream>>>(sh_w, sh_b, pm_w1, pm_b1, w1e, b1e);
        gather_mfma_kernel<<<NN/NPB, 256, 0, stream>>>(
            pos, sdj, start, rbf_c, rbf_w, w1e, b1e, pm_w2, pm_b2, agg);
    } else {
        hipMemsetAsync(agg, 0, (size_t)NN * 64 * sizeof(float), stream);
        edge_kernel<<<NE/256, 256, 0, stream>>>(
            pos, ei, rbf_c, rbf_w, sh_w, sh_b, pm_w1, pm_b1, pm_w2, pm_b2, agg);
    }

    out_kernel<<<512, 256, 0, stream>>>(
        agg, zn_f, np_w, np_b, ln_g, ln_b, out);
}